// Round 1
// baseline (1240.140 us; speedup 1.0000x reference)
//
#include <hip/hip_runtime.h>
#include <hip/hip_bf16.h>
#include <math.h>

using bf16 = __hip_bfloat16;
typedef __bf16 bf16x8 __attribute__((ext_vector_type(8)));
typedef float  f32x4  __attribute__((ext_vector_type(4)));

#define BM 128
#define BN 128
#define BK 32

// ---------------------------------------------------------------------------
// Catmull-Rom spline reconstruction: cp[n_ctrl] -> w[n] (bf16)
// Replicates np.linspace(0, n_ctrl-1, n) in float64: t = k*step.
// ---------------------------------------------------------------------------
__global__ void spline_recon_kernel(const float* __restrict__ cp,
                                    bf16* __restrict__ w,
                                    int n, int n_ctrl, double step) {
    int k = blockIdx.x * blockDim.x + threadIdx.x;
    if (k >= n) return;
    double t = (double)k * step;
    int i = (int)t;                       // floor, t >= 0
    if (i > n_ctrl - 2) i = n_ctrl - 2;
    float f = (float)(t - (double)i);
    float p0 = cp[i > 0 ? i - 1 : 0];
    float p1 = cp[i];
    float p2 = cp[i + 1];
    float p3 = cp[(i + 2) <= (n_ctrl - 1) ? (i + 2) : (n_ctrl - 1)];
    float f2 = f * f;
    float f3 = f2 * f;
    float v = 0.5f * (2.0f * p1
                      + (p2 - p0) * f
                      + (2.0f * p0 - 5.0f * p1 + 4.0f * p2 - p3) * f2
                      + (3.0f * p1 - p0 - 3.0f * p2 + p3) * f3);
    w[k] = __float2bfloat16(v);
}

// fp32 -> bf16 cast for the activations
__global__ void cvt_f32_bf16_kernel(const float* __restrict__ x,
                                    bf16* __restrict__ y, int n) {
    int k = blockIdx.x * blockDim.x + threadIdx.x;
    if (k < n) y[k] = __float2bfloat16(x[k]);
}

// ---------------------------------------------------------------------------
// m97-style bf16 MFMA GEMM, C[m,n] = sum_k A[m,k]*B[n,k]  (B is [N,K] K-major)
// 128x128 block tile, BK=32, 256 threads = 4 waves in 2x2, each wave 4x4
// mfma_f32_16x16x32_bf16 fragments. global_load_lds width-16 staging.
// MODE 0: C=bf16, store silu(acc)
// MODE 1: C=bf16, store bf16_read(C)*acc   (fused silu(gate)*up)
// MODE 2: C=fp32, store acc
// ---------------------------------------------------------------------------
__device__ __forceinline__ void async_load16(const bf16* g, bf16* l) {
    __builtin_amdgcn_global_load_lds(
        (const __attribute__((address_space(1))) void*)g,
        (__attribute__((address_space(3))) void*)l,
        16, 0, 0);
}

template <int MODE>
__global__ __launch_bounds__(256, 3) void gemm_bt_kernel(
    const bf16* __restrict__ A,   // [M, K]
    const bf16* __restrict__ B,   // [N, K]
    void* __restrict__ Cv,
    int M, int N, int K) {
    __shared__ bf16 As[BM * BK];
    __shared__ bf16 Bs[BN * BK];

    const int tid  = threadIdx.x;
    const int lane = tid & 63;
    const int wave = tid >> 6;
    const int wm = (wave >> 1) * 64;   // wave row offset within tile
    const int wn = (wave & 1) * 64;    // wave col offset within tile

    const long long brow = (long long)blockIdx.y * BM;
    const long long bcol = (long long)blockIdx.x * BN;

    // staging: 512 chunks of 16B per 128x32 tile; 2 chunks/thread.
    // chunk c -> LDS elems [c*8, c*8+8) == row-major [c>>2][(c&3)*8 ..]
    const int srow = tid >> 2;            // 0..63
    const int skb  = (tid & 3) * 8;       // bf16 col offset
    const bf16* ga0 = A + (brow + srow) * (long long)K + skb;
    const bf16* ga1 = A + (brow + srow + 64) * (long long)K + skb;
    const bf16* gb0 = B + (bcol + srow) * (long long)K + skb;
    const bf16* gb1 = B + (bcol + srow + 64) * (long long)K + skb;
    bf16* la0 = As + tid * 8;
    bf16* la1 = As + 2048 + tid * 8;
    bf16* lb0 = Bs + tid * 8;
    bf16* lb1 = Bs + 2048 + tid * 8;

    // MFMA fragment addressing (16x16x32):
    // A-frag: lane holds A[m=lane&15][k=(lane>>4)*8 + j]
    // B-frag (as [n][k] rows): lane holds W[n=lane&15][k=(lane>>4)*8 + j]
    const int fm = wm + (lane & 15);
    const int fn = wn + (lane & 15);
    const int fk = (lane >> 4) * 8;

    f32x4 acc[4][4] = {};

    for (int k0 = 0; k0 < K; k0 += BK) {
        async_load16(ga0, la0);
        async_load16(ga1, la1);
        async_load16(gb0, lb0);
        async_load16(gb1, lb1);
        ga0 += BK; ga1 += BK; gb0 += BK; gb1 += BK;
        __syncthreads();   // drains vmcnt for global_load_lds

        bf16x8 afr[4], bfr[4];
#pragma unroll
        for (int i = 0; i < 4; ++i)
            afr[i] = *reinterpret_cast<const bf16x8*>(&As[(fm + i * 16) * BK + fk]);
#pragma unroll
        for (int j = 0; j < 4; ++j)
            bfr[j] = *reinterpret_cast<const bf16x8*>(&Bs[(fn + j * 16) * BK + fk]);

#pragma unroll
        for (int i = 0; i < 4; ++i)
#pragma unroll
            for (int j = 0; j < 4; ++j)
                acc[i][j] = __builtin_amdgcn_mfma_f32_16x16x32_bf16(
                    afr[i], bfr[j], acc[i][j], 0, 0, 0);
        __syncthreads();   // protect LDS before next staging
    }

    // epilogue: C/D layout col=lane&15, row=(lane>>4)*4+reg
#pragma unroll
    for (int i = 0; i < 4; ++i) {
#pragma unroll
        for (int j = 0; j < 4; ++j) {
#pragma unroll
            for (int r = 0; r < 4; ++r) {
                long long row = brow + wm + i * 16 + (lane >> 4) * 4 + r;
                long long col = bcol + wn + j * 16 + (lane & 15);
                float v = acc[i][j][r];
                if constexpr (MODE == 0) {
                    float s = v / (1.0f + expf(-v));    // silu(gate)
                    ((bf16*)Cv)[row * N + col] = __float2bfloat16(s);
                } else if constexpr (MODE == 1) {
                    bf16* C = (bf16*)Cv;
                    float s = __bfloat162float(C[row * N + col]);
                    C[row * N + col] = __float2bfloat16(s * v);
                } else {
                    ((float*)Cv)[row * N + col] = v;
                }
            }
        }
    }
}

// ---------------------------------------------------------------------------
extern "C" void kernel_launch(void* const* d_in, const int* in_sizes, int n_in,
                              void* d_out, int out_size, void* d_ws, size_t ws_size,
                              hipStream_t stream) {
    const float* hs  = (const float*)d_in[0];   // [4,2048,2048] fp32
    const float* gcp = (const float*)d_in[1];
    const float* ucp = (const float*)d_in[2];
    const float* dcp = (const float*)d_in[3];

    const int M = 8192;        // 4*2048 tokens
    const int H = 2048;
    const int I = 8192;
    const int NW = H * I;      // 16,777,216 weight elements per matrix
    const int n_ctrl_g = in_sizes[1];
    const int n_ctrl_u = in_sizes[2];
    const int n_ctrl_d = in_sizes[3];

    // workspace layout (all bf16): Xb | Wg | Wu | Wd | inter  == 256 MB
    bf16* Xb    = (bf16*)d_ws;
    bf16* Wg    = Xb + (size_t)M * H;
    bf16* Wu    = Wg + (size_t)NW;
    bf16* Wd    = Wu + (size_t)NW;
    bf16* inter = Wd + (size_t)NW;

    const int nX = M * H;
    cvt_f32_bf16_kernel<<<(nX + 255) / 256, 256, 0, stream>>>(hs, Xb, nX);

    double step_g = (double)(n_ctrl_g - 1) / (double)(NW - 1);
    double step_u = (double)(n_ctrl_u - 1) / (double)(NW - 1);
    double step_d = (double)(n_ctrl_d - 1) / (double)(NW - 1);
    spline_recon_kernel<<<(NW + 255) / 256, 256, 0, stream>>>(gcp, Wg, NW, n_ctrl_g, step_g);
    spline_recon_kernel<<<(NW + 255) / 256, 256, 0, stream>>>(ucp, Wu, NW, n_ctrl_u, step_u);
    spline_recon_kernel<<<(NW + 255) / 256, 256, 0, stream>>>(dcp, Wd, NW, n_ctrl_d, step_d);

    // gate: inter = silu(X . Wg^T)            [M, I]
    gemm_bt_kernel<0><<<dim3(I / BN, M / BM), 256, 0, stream>>>(Xb, Wg, (void*)inter, M, I, H);
    // up:   inter = inter * (X . Wu^T)        [M, I]
    gemm_bt_kernel<1><<<dim3(I / BN, M / BM), 256, 0, stream>>>(Xb, Wu, (void*)inter, M, I, H);
    // down: out = inter . Wd^T  (fp32)        [M, H]
    gemm_bt_kernel<2><<<dim3(H / BN, M / BM), 256, 0, stream>>>(inter, Wd, d_out, M, H, I);
}

// Round 2
// 1081.999 us; speedup vs baseline: 1.1462x; 1.1462x over previous
//
#include <hip/hip_runtime.h>
#include <hip/hip_bf16.h>
#include <math.h>

using bf16 = __hip_bfloat16;
typedef __bf16 bf16x8 __attribute__((ext_vector_type(8)));
typedef float  f32x4  __attribute__((ext_vector_type(4)));

#define BM 128
#define BN 128
#define BK 32

// ---------------------------------------------------------------------------
// Catmull-Rom spline reconstruction: cp[n_ctrl] -> w[n] (bf16), 8 outputs/thread.
// Replicates np.linspace(0, n_ctrl-1, n) in float64: t = k*step.
// ---------------------------------------------------------------------------
__global__ void spline_recon8_kernel(const float* __restrict__ cp,
                                     bf16* __restrict__ w,
                                     int n8, int n_ctrl, double step) {
    int k8 = blockIdx.x * blockDim.x + threadIdx.x;
    if (k8 >= n8) return;
    long long kbase = (long long)k8 * 8;
    bf16x8 o;
#pragma unroll
    for (int u = 0; u < 8; ++u) {
        double t = (double)(kbase + u) * step;
        int i = (int)t;                       // floor, t >= 0
        if (i > n_ctrl - 2) i = n_ctrl - 2;
        float f = (float)(t - (double)i);
        float p0 = cp[i > 0 ? i - 1 : 0];
        float p1 = cp[i];
        float p2 = cp[i + 1];
        float p3 = cp[(i + 2) <= (n_ctrl - 1) ? (i + 2) : (n_ctrl - 1)];
        float f2 = f * f;
        float f3 = f2 * f;
        float v = 0.5f * (2.0f * p1
                          + (p2 - p0) * f
                          + (2.0f * p0 - 5.0f * p1 + 4.0f * p2 - p3) * f2
                          + (3.0f * p1 - p0 - 3.0f * p2 + p3) * f3);
        o[u] = (__bf16)v;
    }
    *reinterpret_cast<bf16x8*>(w + kbase) = o;   // 16B aligned (kbase % 8 == 0)
}

// fp32 -> bf16 cast, 8 elements/thread (32B read, 16B write)
__global__ void cvt_f32_bf16_8_kernel(const float4* __restrict__ x,
                                      bf16* __restrict__ y, int n8) {
    int k = blockIdx.x * blockDim.x + threadIdx.x;
    if (k >= n8) return;
    float4 a = x[2 * k];
    float4 b = x[2 * k + 1];
    bf16x8 o;
    o[0] = (__bf16)a.x; o[1] = (__bf16)a.y; o[2] = (__bf16)a.z; o[3] = (__bf16)a.w;
    o[4] = (__bf16)b.x; o[5] = (__bf16)b.y; o[6] = (__bf16)b.z; o[7] = (__bf16)b.w;
    *reinterpret_cast<bf16x8*>(y + (long long)k * 8) = o;
}

__device__ __forceinline__ void async_load16(const bf16* g, bf16* l) {
    __builtin_amdgcn_global_load_lds(
        (const __attribute__((address_space(1))) void*)g,
        (__attribute__((address_space(3))) void*)l,
        16, 0, 0);
}

// ---------------------------------------------------------------------------
// Fused gate+up GEMM: inter[m,n] = silu(X.Wg^T) * (X.Wu^T)
// 512 threads = 8 waves. Waves 0-3 compute gate quadrant 2x2, waves 4-7 up.
// Shared As staging (the A operand is read ONCE for both GEMMs).
// Epilogue: gate waves deposit silu(g) in LDS; up waves multiply and store.
// ---------------------------------------------------------------------------
__global__ __launch_bounds__(512, 4) void fused_gate_up_kernel(
    const bf16* __restrict__ A,    // X  [M, K]
    const bf16* __restrict__ Bg,   // Wg [N, K]
    const bf16* __restrict__ Bu,   // Wu [N, K]
    bf16* __restrict__ C,          // inter [M, N]
    int M, int N, int K) {
    __shared__ __align__(16) bf16 smem[16384];   // 32 KB
    bf16* As  = smem;                            // [128*32]
    bf16* Bgs = smem + 4096;
    bf16* Bus = smem + 8192;

    const int tid  = threadIdx.x;
    const int lane = tid & 63;
    const int wave = tid >> 6;          // 0..7
    const int wq   = wave & 3;
    const int wm   = (wq >> 1) * 64;
    const int wn   = (wq & 1) * 64;
    const bool is_gate = wave < 4;

    const long long brow = (long long)blockIdx.y * BM;
    const long long bcol = (long long)blockIdx.x * BN;

    // staging: 512 threads cover one 16B chunk per tile each
    const int srow = tid >> 2;          // 0..127
    const int skb  = (tid & 3) * 8;
    const bf16* ga = A  + (brow + srow) * (long long)K + skb;
    const bf16* gg = Bg + (bcol + srow) * (long long)K + skb;
    const bf16* gu = Bu + (bcol + srow) * (long long)K + skb;
    bf16* la = As  + tid * 8;
    bf16* lg = Bgs + tid * 8;
    bf16* lu = Bus + tid * 8;

    const bf16* Bsel = is_gate ? Bgs : Bus;
    const int fm = wm + (lane & 15);
    const int fn = wn + (lane & 15);
    const int fk = (lane >> 4) * 8;

    f32x4 acc[4][4] = {};

    for (int k0 = 0; k0 < K; k0 += BK) {
        async_load16(ga, la); ga += BK;
        async_load16(gg, lg); gg += BK;
        async_load16(gu, lu); gu += BK;
        __syncthreads();   // drains vmcnt for global_load_lds

        bf16x8 afr[4], bfr[4];
#pragma unroll
        for (int i = 0; i < 4; ++i)
            afr[i] = *reinterpret_cast<const bf16x8*>(&As[(fm + i * 16) * BK + fk]);
#pragma unroll
        for (int j = 0; j < 4; ++j)
            bfr[j] = *reinterpret_cast<const bf16x8*>(&Bsel[(fn + j * 16) * BK + fk]);

#pragma unroll
        for (int i = 0; i < 4; ++i)
#pragma unroll
            for (int j = 0; j < 4; ++j)
                acc[i][j] = __builtin_amdgcn_mfma_f32_16x16x32_bf16(
                    afr[i], bfr[j], acc[i][j], 0, 0, 0);
        __syncthreads();
    }

    // Epilogue: combine silu(gate)*up through LDS (reuses smem as Epi[128][128])
    bf16* Epi = smem;
    if (is_gate) {
#pragma unroll
        for (int i = 0; i < 4; ++i)
#pragma unroll
            for (int j = 0; j < 4; ++j)
#pragma unroll
                for (int r = 0; r < 4; ++r) {
                    int row = wm + i * 16 + (lane >> 4) * 4 + r;
                    int col = wn + j * 16 + (lane & 15);
                    float v = acc[i][j][r];
                    float s = v / (1.0f + expf(-v));
                    Epi[row * 128 + col] = __float2bfloat16(s);
                }
    }
    __syncthreads();
    if (!is_gate) {
#pragma unroll
        for (int i = 0; i < 4; ++i)
#pragma unroll
            for (int j = 0; j < 4; ++j)
#pragma unroll
                for (int r = 0; r < 4; ++r) {
                    int row = wm + i * 16 + (lane >> 4) * 4 + r;
                    int col = wn + j * 16 + (lane & 15);
                    float s = __bfloat162float(Epi[row * 128 + col]);
                    float v = s * acc[i][j][r];
                    C[(brow + row) * (long long)N + bcol + col] = __float2bfloat16(v);
                }
    }
}

// ---------------------------------------------------------------------------
// down GEMM: out[m,n] = sum_k inter[m,k] * Wd[n,k], fp32 out
// ---------------------------------------------------------------------------
__global__ __launch_bounds__(256, 4) void gemm_down_kernel(
    const bf16* __restrict__ A,   // inter [M, K]
    const bf16* __restrict__ B,   // Wd    [N, K]
    float* __restrict__ C,        // out   [M, N]
    int M, int N, int K) {
    __shared__ __align__(16) bf16 As[BM * BK];
    __shared__ __align__(16) bf16 Bs[BN * BK];

    const int tid  = threadIdx.x;
    const int lane = tid & 63;
    const int wave = tid >> 6;
    const int wm = (wave >> 1) * 64;
    const int wn = (wave & 1) * 64;

    const long long brow = (long long)blockIdx.y * BM;
    const long long bcol = (long long)blockIdx.x * BN;

    const int srow = tid >> 2;
    const int skb  = (tid & 3) * 8;
    const bf16* ga0 = A + (brow + srow) * (long long)K + skb;
    const bf16* ga1 = A + (brow + srow + 64) * (long long)K + skb;
    const bf16* gb0 = B + (bcol + srow) * (long long)K + skb;
    const bf16* gb1 = B + (bcol + srow + 64) * (long long)K + skb;
    bf16* la0 = As + tid * 8;
    bf16* la1 = As + 2048 + tid * 8;
    bf16* lb0 = Bs + tid * 8;
    bf16* lb1 = Bs + 2048 + tid * 8;

    const int fm = wm + (lane & 15);
    const int fn = wn + (lane & 15);
    const int fk = (lane >> 4) * 8;

    f32x4 acc[4][4] = {};

    for (int k0 = 0; k0 < K; k0 += BK) {
        async_load16(ga0, la0);
        async_load16(ga1, la1);
        async_load16(gb0, lb0);
        async_load16(gb1, lb1);
        ga0 += BK; ga1 += BK; gb0 += BK; gb1 += BK;
        __syncthreads();

        bf16x8 afr[4], bfr[4];
#pragma unroll
        for (int i = 0; i < 4; ++i)
            afr[i] = *reinterpret_cast<const bf16x8*>(&As[(fm + i * 16) * BK + fk]);
#pragma unroll
        for (int j = 0; j < 4; ++j)
            bfr[j] = *reinterpret_cast<const bf16x8*>(&Bs[(fn + j * 16) * BK + fk]);

#pragma unroll
        for (int i = 0; i < 4; ++i)
#pragma unroll
            for (int j = 0; j < 4; ++j)
                acc[i][j] = __builtin_amdgcn_mfma_f32_16x16x32_bf16(
                    afr[i], bfr[j], acc[i][j], 0, 0, 0);
        __syncthreads();
    }

#pragma unroll
    for (int i = 0; i < 4; ++i)
#pragma unroll
        for (int j = 0; j < 4; ++j)
#pragma unroll
            for (int r = 0; r < 4; ++r) {
                long long row = brow + wm + i * 16 + (lane >> 4) * 4 + r;
                long long col = bcol + wn + j * 16 + (lane & 15);
                C[row * N + col] = acc[i][j][r];
            }
}

// ---------------------------------------------------------------------------
extern "C" void kernel_launch(void* const* d_in, const int* in_sizes, int n_in,
                              void* d_out, int out_size, void* d_ws, size_t ws_size,
                              hipStream_t stream) {
    const float* hs  = (const float*)d_in[0];   // [4,2048,2048] fp32
    const float* gcp = (const float*)d_in[1];
    const float* ucp = (const float*)d_in[2];
    const float* dcp = (const float*)d_in[3];

    const int M = 8192;        // 4*2048 tokens
    const int H = 2048;
    const int I = 8192;
    const int NW = H * I;      // 16,777,216 weight elements per matrix
    const int n_ctrl_g = in_sizes[1];
    const int n_ctrl_u = in_sizes[2];
    const int n_ctrl_d = in_sizes[3];

    // workspace layout (all bf16): Xb | Wg | Wu | Wd | inter
    bf16* Xb    = (bf16*)d_ws;
    bf16* Wg    = Xb + (size_t)M * H;
    bf16* Wu    = Wg + (size_t)NW;
    bf16* Wd    = Wu + (size_t)NW;
    bf16* inter = Wd + (size_t)NW;

    const int nX8 = (M * H) / 8;
    cvt_f32_bf16_8_kernel<<<(nX8 + 255) / 256, 256, 0, stream>>>(
        (const float4*)hs, Xb, nX8);

    double step_g = (double)(n_ctrl_g - 1) / (double)(NW - 1);
    double step_u = (double)(n_ctrl_u - 1) / (double)(NW - 1);
    double step_d = (double)(n_ctrl_d - 1) / (double)(NW - 1);
    const int n8 = NW / 8;
    spline_recon8_kernel<<<(n8 + 255) / 256, 256, 0, stream>>>(gcp, Wg, n8, n_ctrl_g, step_g);
    spline_recon8_kernel<<<(n8 + 255) / 256, 256, 0, stream>>>(ucp, Wu, n8, n_ctrl_u, step_u);
    spline_recon8_kernel<<<(n8 + 255) / 256, 256, 0, stream>>>(dcp, Wd, n8, n_ctrl_d, step_d);

    // fused gate+up: inter = silu(X.Wg^T) * (X.Wu^T)   [M, I]
    fused_gate_up_kernel<<<dim3(I / BN, M / BM), 512, 0, stream>>>(
        Xb, Wg, Wu, inter, M, I, H);

    // down: out = inter . Wd^T  (fp32)   [M, H]
    gemm_down_kernel<<<dim3(H / BN, M / BM), 256, 0, stream>>>(
        inter, Wd, (float*)d_out, M, H, I);
}

// Round 3
// 1065.493 us; speedup vs baseline: 1.1639x; 1.0155x over previous
//
#include <hip/hip_runtime.h>
#include <hip/hip_bf16.h>
#include <math.h>

using bf16 = __hip_bfloat16;
typedef __bf16 bf16x8 __attribute__((ext_vector_type(8)));
typedef float  f32x4  __attribute__((ext_vector_type(4)));

#define BM 128
#define BN 128
#define BK 32

// ---------------------------------------------------------------------------
// Catmull-Rom spline reconstruction: cp[n_ctrl] -> w[n] (bf16), 8 outputs/thread.
// Replicates np.linspace(0, n_ctrl-1, n) in float64: t = k*step.
// ---------------------------------------------------------------------------
__global__ void spline_recon8_kernel(const float* __restrict__ cp,
                                     bf16* __restrict__ w,
                                     int n8, int n_ctrl, double step) {
    int k8 = blockIdx.x * blockDim.x + threadIdx.x;
    if (k8 >= n8) return;
    long long kbase = (long long)k8 * 8;
    bf16x8 o;
#pragma unroll
    for (int u = 0; u < 8; ++u) {
        double t = (double)(kbase + u) * step;
        int i = (int)t;                       // floor, t >= 0
        if (i > n_ctrl - 2) i = n_ctrl - 2;
        float f = (float)(t - (double)i);
        float p0 = cp[i > 0 ? i - 1 : 0];
        float p1 = cp[i];
        float p2 = cp[i + 1];
        float p3 = cp[(i + 2) <= (n_ctrl - 1) ? (i + 2) : (n_ctrl - 1)];
        float f2 = f * f;
        float f3 = f2 * f;
        float v = 0.5f * (2.0f * p1
                          + (p2 - p0) * f
                          + (2.0f * p0 - 5.0f * p1 + 4.0f * p2 - p3) * f2
                          + (3.0f * p1 - p0 - 3.0f * p2 + p3) * f3);
        o[u] = (__bf16)v;
    }
    *reinterpret_cast<bf16x8*>(w + kbase) = o;   // 16B aligned (kbase % 8 == 0)
}

// fp32 -> bf16 cast, 8 elements/thread (32B read, 16B write)
__global__ void cvt_f32_bf16_8_kernel(const float4* __restrict__ x,
                                      bf16* __restrict__ y, int n8) {
    int k = blockIdx.x * blockDim.x + threadIdx.x;
    if (k >= n8) return;
    float4 a = x[2 * k];
    float4 b = x[2 * k + 1];
    bf16x8 o;
    o[0] = (__bf16)a.x; o[1] = (__bf16)a.y; o[2] = (__bf16)a.z; o[3] = (__bf16)a.w;
    o[4] = (__bf16)b.x; o[5] = (__bf16)b.y; o[6] = (__bf16)b.z; o[7] = (__bf16)b.w;
    *reinterpret_cast<bf16x8*>(y + (long long)k * 8) = o;
}

__device__ __forceinline__ void async_load16(const bf16* g, bf16* l) {
    __builtin_amdgcn_global_load_lds(
        (const __attribute__((address_space(1))) void*)g,
        (__attribute__((address_space(3))) void*)l,
        16, 0, 0);
}

// ---------------------------------------------------------------------------
// Fused gate+up GEMM: inter[m,n] = silu(X.Wg^T) * (X.Wu^T)
// 512 threads = 8 waves. Waves 0-3 compute gate quadrant 2x2, waves 4-7 up.
// Shared As staging (the A operand is read ONCE for both GEMMs).
// Epilogue: gate waves deposit silu(g) in LDS; up waves multiply and store.
// Measured R2: ~627 us, 877 TF effective (m97-structure plateau).
// ---------------------------------------------------------------------------
__global__ __launch_bounds__(512, 4) void fused_gate_up_kernel(
    const bf16* __restrict__ A,    // X  [M, K]
    const bf16* __restrict__ Bg,   // Wg [N, K]
    const bf16* __restrict__ Bu,   // Wu [N, K]
    bf16* __restrict__ C,          // inter [M, N]
    int M, int N, int K) {
    __shared__ __align__(16) bf16 smem[16384];   // 32 KB (epilogue reuses all of it)
    bf16* As  = smem;                            // [128*32]
    bf16* Bgs = smem + 4096;
    bf16* Bus = smem + 8192;

    const int tid  = threadIdx.x;
    const int lane = tid & 63;
    const int wave = tid >> 6;          // 0..7
    const int wq   = wave & 3;
    const int wm   = (wq >> 1) * 64;
    const int wn   = (wq & 1) * 64;
    const bool is_gate = wave < 4;

    const long long brow = (long long)blockIdx.y * BM;
    const long long bcol = (long long)blockIdx.x * BN;

    // staging: 512 threads cover one 16B chunk per tile each
    const int srow = tid >> 2;          // 0..127
    const int skb  = (tid & 3) * 8;
    const bf16* ga = A  + (brow + srow) * (long long)K + skb;
    const bf16* gg = Bg + (bcol + srow) * (long long)K + skb;
    const bf16* gu = Bu + (bcol + srow) * (long long)K + skb;
    bf16* la = As  + tid * 8;
    bf16* lg = Bgs + tid * 8;
    bf16* lu = Bus + tid * 8;

    const bf16* Bsel = is_gate ? Bgs : Bus;
    const int fm = wm + (lane & 15);
    const int fn = wn + (lane & 15);
    const int fk = (lane >> 4) * 8;

    f32x4 acc[4][4] = {};

    for (int k0 = 0; k0 < K; k0 += BK) {
        async_load16(ga, la); ga += BK;
        async_load16(gg, lg); gg += BK;
        async_load16(gu, lu); gu += BK;
        __syncthreads();   // drains vmcnt for global_load_lds

        bf16x8 afr[4], bfr[4];
#pragma unroll
        for (int i = 0; i < 4; ++i)
            afr[i] = *reinterpret_cast<const bf16x8*>(&As[(fm + i * 16) * BK + fk]);
#pragma unroll
        for (int j = 0; j < 4; ++j)
            bfr[j] = *reinterpret_cast<const bf16x8*>(&Bsel[(fn + j * 16) * BK + fk]);

#pragma unroll
        for (int i = 0; i < 4; ++i)
#pragma unroll
            for (int j = 0; j < 4; ++j)
                acc[i][j] = __builtin_amdgcn_mfma_f32_16x16x32_bf16(
                    afr[i], bfr[j], acc[i][j], 0, 0, 0);
        __syncthreads();
    }

    // Epilogue: combine silu(gate)*up through LDS (reuses smem as Epi[128][128])
    bf16* Epi = smem;
    if (is_gate) {
#pragma unroll
        for (int i = 0; i < 4; ++i)
#pragma unroll
            for (int j = 0; j < 4; ++j)
#pragma unroll
                for (int r = 0; r < 4; ++r) {
                    int row = wm + i * 16 + (lane >> 4) * 4 + r;
                    int col = wn + j * 16 + (lane & 15);
                    float v = acc[i][j][r];
                    float s = v / (1.0f + expf(-v));
                    Epi[row * 128 + col] = __float2bfloat16(s);
                }
    }
    __syncthreads();
    if (!is_gate) {
#pragma unroll
        for (int i = 0; i < 4; ++i)
#pragma unroll
            for (int j = 0; j < 4; ++j)
#pragma unroll
                for (int r = 0; r < 4; ++r) {
                    int row = wm + i * 16 + (lane >> 4) * 4 + r;
                    int col = wn + j * 16 + (lane & 15);
                    float s = __bfloat162float(Epi[row * 128 + col]);
                    float v = s * acc[i][j][r];
                    C[(brow + row) * (long long)N + bcol + col] = __float2bfloat16(v);
                }
    }
}

// ---------------------------------------------------------------------------
// down GEMM, R3 restructure: 512 threads, 128(M) x 256(N) tile, shared As.
// Waves 0-3 cover B cols 0-127 (2x2 of 64x64), waves 4-7 cover cols 128-255.
// Per K-step: stage 24KB (As 8K + Bs 16K) for 2.1 MFLOP — same profile as the
// fused kernel's measured 877 TF.
// ---------------------------------------------------------------------------
__global__ __launch_bounds__(512, 4) void gemm_down2_kernel(
    const bf16* __restrict__ A,   // inter [M, K]
    const bf16* __restrict__ B,   // Wd    [N, K]
    float* __restrict__ C,        // out   [M, N]
    int M, int N, int K) {
    __shared__ __align__(16) bf16 As[128 * BK];   // 8 KB
    __shared__ __align__(16) bf16 Bs[256 * BK];   // 16 KB

    const int tid  = threadIdx.x;
    const int lane = tid & 63;
    const int wave = tid >> 6;           // 0..7
    const int half = wave >> 2;          // which 128-col half of B
    const int wq   = wave & 3;
    const int wm   = (wq >> 1) * 64;
    const int wn   = half * 128 + (wq & 1) * 64;

    const long long brow = (long long)blockIdx.y * 128;
    const long long bcol = (long long)blockIdx.x * 256;

    // staging: As = 512 chunks (1/thread), Bs = 1024 chunks (2/thread)
    const int srow = tid >> 2;           // 0..127
    const int skb  = (tid & 3) * 8;
    const bf16* ga  = A + (brow + srow) * (long long)K + skb;
    const bf16* gb0 = B + (bcol + srow) * (long long)K + skb;
    const bf16* gb1 = B + (bcol + srow + 128) * (long long)K + skb;
    bf16* la  = As + tid * 8;
    bf16* lb0 = Bs + tid * 8;
    bf16* lb1 = Bs + 4096 + tid * 8;

    const int fm = wm + (lane & 15);
    const int fn = wn + (lane & 15);     // row index into Bs [256][32]
    const int fk = (lane >> 4) * 8;

    f32x4 acc[4][4] = {};

    for (int k0 = 0; k0 < K; k0 += BK) {
        async_load16(ga, la);   ga  += BK;
        async_load16(gb0, lb0); gb0 += BK;
        async_load16(gb1, lb1); gb1 += BK;
        __syncthreads();

        bf16x8 afr[4], bfr[4];
#pragma unroll
        for (int i = 0; i < 4; ++i)
            afr[i] = *reinterpret_cast<const bf16x8*>(&As[(fm + i * 16) * BK + fk]);
#pragma unroll
        for (int j = 0; j < 4; ++j)
            bfr[j] = *reinterpret_cast<const bf16x8*>(&Bs[(fn + j * 16) * BK + fk]);

#pragma unroll
        for (int i = 0; i < 4; ++i)
#pragma unroll
            for (int j = 0; j < 4; ++j)
                acc[i][j] = __builtin_amdgcn_mfma_f32_16x16x32_bf16(
                    afr[i], bfr[j], acc[i][j], 0, 0, 0);
        __syncthreads();
    }

#pragma unroll
    for (int i = 0; i < 4; ++i)
#pragma unroll
        for (int j = 0; j < 4; ++j)
#pragma unroll
            for (int r = 0; r < 4; ++r) {
                long long row = brow + wm + i * 16 + (lane >> 4) * 4 + r;
                long long col = bcol + wn + j * 16 + (lane & 15);
                C[row * N + col] = acc[i][j][r];
            }
}

// ---------------------------------------------------------------------------
extern "C" void kernel_launch(void* const* d_in, const int* in_sizes, int n_in,
                              void* d_out, int out_size, void* d_ws, size_t ws_size,
                              hipStream_t stream) {
    const float* hs  = (const float*)d_in[0];   // [4,2048,2048] fp32
    const float* gcp = (const float*)d_in[1];
    const float* ucp = (const float*)d_in[2];
    const float* dcp = (const float*)d_in[3];

    const int M = 8192;        // 4*2048 tokens
    const int H = 2048;
    const int I = 8192;
    const int NW = H * I;      // 16,777,216 weight elements per matrix
    const int n_ctrl_g = in_sizes[1];
    const int n_ctrl_u = in_sizes[2];
    const int n_ctrl_d = in_sizes[3];

    // workspace layout (all bf16): Xb | Wg | Wu | Wd | inter
    bf16* Xb    = (bf16*)d_ws;
    bf16* Wg    = Xb + (size_t)M * H;
    bf16* Wu    = Wg + (size_t)NW;
    bf16* Wd    = Wu + (size_t)NW;
    bf16* inter = Wd + (size_t)NW;

    const int nX8 = (M * H) / 8;
    cvt_f32_bf16_8_kernel<<<(nX8 + 255) / 256, 256, 0, stream>>>(
        (const float4*)hs, Xb, nX8);

    double step_g = (double)(n_ctrl_g - 1) / (double)(NW - 1);
    double step_u = (double)(n_ctrl_u - 1) / (double)(NW - 1);
    double step_d = (double)(n_ctrl_d - 1) / (double)(NW - 1);
    const int n8 = NW / 8;
    spline_recon8_kernel<<<(n8 + 255) / 256, 256, 0, stream>>>(gcp, Wg, n8, n_ctrl_g, step_g);
    spline_recon8_kernel<<<(n8 + 255) / 256, 256, 0, stream>>>(ucp, Wu, n8, n_ctrl_u, step_u);
    spline_recon8_kernel<<<(n8 + 255) / 256, 256, 0, stream>>>(dcp, Wd, n8, n_ctrl_d, step_d);

    // fused gate+up: inter = silu(X.Wg^T) * (X.Wu^T)   [M, I]
    fused_gate_up_kernel<<<dim3(I / BN, M / BM), 512, 0, stream>>>(
        Xb, Wg, Wu, inter, M, I, H);

    // down: out = inter . Wd^T  (fp32)   [M, H], 128x256 tiles
    gemm_down2_kernel<<<dim3(H / 256, M / 128), 512, 0, stream>>>(
        inter, Wd, (float*)d_out, M, H, I);
}

// Round 5
// 922.640 us; speedup vs baseline: 1.3441x; 1.1548x over previous
//
#include <hip/hip_runtime.h>
#include <hip/hip_bf16.h>
#include <math.h>

using bf16 = __hip_bfloat16;
typedef __bf16 bf16x8 __attribute__((ext_vector_type(8)));
typedef float  f32x4  __attribute__((ext_vector_type(4)));

#define BK 64   // K-tile; row stride 128B, XOR-swizzled chunks

// ---------------------------------------------------------------------------
// Catmull-Rom spline reconstruction: cp[n_ctrl] -> w[n] (bf16), 8 outputs/thread.
// Replicates np.linspace(0, n_ctrl-1, n) in float64: t = k*step.
// ---------------------------------------------------------------------------
__global__ void spline_recon8_kernel(const float* __restrict__ cp,
                                     bf16* __restrict__ w,
                                     int n8, int n_ctrl, double step) {
    int k8 = blockIdx.x * blockDim.x + threadIdx.x;
    if (k8 >= n8) return;
    long long kbase = (long long)k8 * 8;
    bf16x8 o;
#pragma unroll
    for (int u = 0; u < 8; ++u) {
        double t = (double)(kbase + u) * step;
        int i = (int)t;                       // floor, t >= 0
        if (i > n_ctrl - 2) i = n_ctrl - 2;
        float f = (float)(t - (double)i);
        float p0 = cp[i > 0 ? i - 1 : 0];
        float p1 = cp[i];
        float p2 = cp[i + 1];
        float p3 = cp[(i + 2) <= (n_ctrl - 1) ? (i + 2) : (n_ctrl - 1)];
        float f2 = f * f;
        float f3 = f2 * f;
        float v = 0.5f * (2.0f * p1
                          + (p2 - p0) * f
                          + (2.0f * p0 - 5.0f * p1 + 4.0f * p2 - p3) * f2
                          + (3.0f * p1 - p0 - 3.0f * p2 + p3) * f3);
        o[u] = (__bf16)v;
    }
    *reinterpret_cast<bf16x8*>(w + kbase) = o;
}

// fp32 -> bf16 cast, 8 elements/thread
__global__ void cvt_f32_bf16_8_kernel(const float4* __restrict__ x,
                                      bf16* __restrict__ y, int n8) {
    int k = blockIdx.x * blockDim.x + threadIdx.x;
    if (k >= n8) return;
    float4 a = x[2 * k];
    float4 b = x[2 * k + 1];
    bf16x8 o;
    o[0] = (__bf16)a.x; o[1] = (__bf16)a.y; o[2] = (__bf16)a.z; o[3] = (__bf16)a.w;
    o[4] = (__bf16)b.x; o[5] = (__bf16)b.y; o[6] = (__bf16)b.z; o[7] = (__bf16)b.w;
    *reinterpret_cast<bf16x8*>(y + (long long)k * 8) = o;
}

__device__ __forceinline__ void async_load16(const bf16* g, bf16* l) {
    __builtin_amdgcn_global_load_lds(
        (const __attribute__((address_space(1))) void*)g,
        (__attribute__((address_space(3))) void*)l,
        16, 0, 0);
}

// ---------------------------------------------------------------------------
// Fused gate+up GEMM: inter[m,n] = silu(X.Wg^T) * (X.Wu^T)
// 512 threads = 8 waves: waves 0-3 gate, 4-7 up; shared As stage.
// BK=64, tiles [128][64] bf16, XOR-swizzled: LDS[row][cc] = G[row][cc^(row&7)]
// (swizzle applied on the GLOBAL source address; LDS dest stays lane-linear).
// ---------------------------------------------------------------------------
__global__ __launch_bounds__(512, 4) void fused_gate_up_kernel(
    const bf16* __restrict__ A,    // X  [M, K]
    const bf16* __restrict__ Bg,   // Wg [N, K]
    const bf16* __restrict__ Bu,   // Wu [N, K]
    bf16* __restrict__ C,          // inter [M, N]
    int M, int N, int K) {
    __shared__ __align__(16) bf16 smem[3 * 128 * BK];   // 48 KB
    bf16* As  = smem;
    bf16* Bgs = smem + 128 * BK;
    bf16* Bus = smem + 2 * 128 * BK;

    const int tid  = threadIdx.x;
    const int lane = tid & 63;
    const int wave = tid >> 6;
    const int wq   = wave & 3;
    const int wm   = (wq >> 1) * 64;
    const int wn   = (wq & 1) * 64;
    const bool is_gate = wave < 4;

    const long long brow = (long long)blockIdx.y * 128;
    const long long bcol = (long long)blockIdx.x * 128;

    // staging: per tile 1024 chunks of 16B; 2 issues/thread/tile.
    // chunk c -> row = c>>3 (+64 for 2nd issue), LDS colchunk = c&7,
    // global colchunk = (c&7) ^ (row&7)  [row&7 identical for both issues]
    const int srow = tid >> 3;                       // 0..63
    const int skb  = ((tid & 7) ^ (srow & 7)) * 8;   // swizzled global col (elems)
    const bf16* ga0 = A  + (brow + srow) * (long long)K + skb;
    const bf16* ga1 = A  + (brow + srow + 64) * (long long)K + skb;
    const bf16* gg0 = Bg + (bcol + srow) * (long long)K + skb;
    const bf16* gg1 = Bg + (bcol + srow + 64) * (long long)K + skb;
    const bf16* gu0 = Bu + (bcol + srow) * (long long)K + skb;
    const bf16* gu1 = Bu + (bcol + srow + 64) * (long long)K + skb;
    bf16* la0 = As  + tid * 8;
    bf16* la1 = As  + 4096 + tid * 8;
    bf16* lg0 = Bgs + tid * 8;
    bf16* lg1 = Bgs + 4096 + tid * 8;
    bf16* lu0 = Bus + tid * 8;
    bf16* lu1 = Bus + 4096 + tid * 8;

    const bf16* Bsel = is_gate ? Bgs : Bus;
    const int fm = wm + (lane & 15);
    const int fn = wn + (lane & 15);
    const int qk = lane >> 4;              // 0..3 (k-quad)

    f32x4 acc[4][4] = {};

    for (int k0 = 0; k0 < K; k0 += BK) {
        async_load16(ga0, la0); ga0 += BK;
        async_load16(ga1, la1); ga1 += BK;
        async_load16(gg0, lg0); gg0 += BK;
        async_load16(gg1, lg1); gg1 += BK;
        async_load16(gu0, lu0); gu0 += BK;
        async_load16(gu1, lu1); gu1 += BK;
        __syncthreads();   // drains vmcnt for global_load_lds

#pragma unroll
        for (int h = 0; h < 2; ++h) {
            bf16x8 afr[4], bfr[4];
            const int hc = (h << 2) | qk;          // wanted colchunk 0..7
            const int ccA = (hc ^ (fm & 7)) * 8;   // fm&7 invariant over i (+16)
            const int ccB = (hc ^ (fn & 7)) * 8;
#pragma unroll
            for (int i = 0; i < 4; ++i)
                afr[i] = *reinterpret_cast<const bf16x8*>(
                    &As[(fm + i * 16) * BK + ccA]);
#pragma unroll
            for (int j = 0; j < 4; ++j)
                bfr[j] = *reinterpret_cast<const bf16x8*>(
                    &Bsel[(fn + j * 16) * BK + ccB]);
#pragma unroll
            for (int i = 0; i < 4; ++i)
#pragma unroll
                for (int j = 0; j < 4; ++j)
                    acc[i][j] = __builtin_amdgcn_mfma_f32_16x16x32_bf16(
                        afr[i], bfr[j], acc[i][j], 0, 0, 0);
        }
        __syncthreads();
    }

    // Epilogue: combine silu(gate)*up through LDS (reuses smem as Epi[128][128])
    bf16* Epi = smem;
    if (is_gate) {
#pragma unroll
        for (int i = 0; i < 4; ++i)
#pragma unroll
            for (int j = 0; j < 4; ++j)
#pragma unroll
                for (int r = 0; r < 4; ++r) {
                    int row = wm + i * 16 + (lane >> 4) * 4 + r;
                    int col = wn + j * 16 + (lane & 15);
                    float v = acc[i][j][r];
                    float s = v / (1.0f + expf(-v));
                    Epi[row * 128 + col] = __float2bfloat16(s);
                }
    }
    __syncthreads();
    if (!is_gate) {
#pragma unroll
        for (int i = 0; i < 4; ++i)
#pragma unroll
            for (int j = 0; j < 4; ++j)
#pragma unroll
                for (int r = 0; r < 4; ++r) {
                    int row = wm + i * 16 + (lane >> 4) * 4 + r;
                    int col = wn + j * 16 + (lane & 15);
                    float s = __bfloat162float(Epi[row * 128 + col]);
                    float v = s * acc[i][j][r];
                    C[(brow + row) * (long long)N + bcol + col] = __float2bfloat16(v);
                }
    }
}

// ---------------------------------------------------------------------------
// down GEMM: 512 threads, 128(M) x 256(N) tile, BK=64, same swizzle.
// ---------------------------------------------------------------------------
__global__ __launch_bounds__(512, 4) void gemm_down2_kernel(
    const bf16* __restrict__ A,   // inter [M, K]
    const bf16* __restrict__ B,   // Wd    [N, K]
    float* __restrict__ C,        // out   [M, N]
    int M, int N, int K) {
    __shared__ __align__(16) bf16 As[128 * BK];   // 16 KB
    __shared__ __align__(16) bf16 Bs[256 * BK];   // 32 KB

    const int tid  = threadIdx.x;
    const int lane = tid & 63;
    const int wave = tid >> 6;
    const int half = wave >> 2;
    const int wq   = wave & 3;
    const int wm   = (wq >> 1) * 64;
    const int wn   = half * 128 + (wq & 1) * 64;

    const long long brow = (long long)blockIdx.y * 128;
    const long long bcol = (long long)blockIdx.x * 256;

    const int srow = tid >> 3;
    const int skb  = ((tid & 7) ^ (srow & 7)) * 8;
    const bf16* ga0 = A + (brow + srow) * (long long)K + skb;
    const bf16* ga1 = A + (brow + srow + 64) * (long long)K + skb;
    const bf16* gb0 = B + (bcol + srow) * (long long)K + skb;
    const bf16* gb1 = B + (bcol + srow + 64) * (long long)K + skb;
    const bf16* gb2 = B + (bcol + srow + 128) * (long long)K + skb;
    const bf16* gb3 = B + (bcol + srow + 192) * (long long)K + skb;
    bf16* la0 = As + tid * 8;
    bf16* la1 = As + 4096 + tid * 8;
    bf16* lb0 = Bs + tid * 8;
    bf16* lb1 = Bs + 4096 + tid * 8;
    bf16* lb2 = Bs + 8192 + tid * 8;
    bf16* lb3 = Bs + 12288 + tid * 8;

    const int fm = wm + (lane & 15);
    const int fn = wn + (lane & 15);
    const int qk = lane >> 4;

    f32x4 acc[4][4] = {};

    for (int k0 = 0; k0 < K; k0 += BK) {
        async_load16(ga0, la0); ga0 += BK;
        async_load16(ga1, la1); ga1 += BK;
        async_load16(gb0, lb0); gb0 += BK;
        async_load16(gb1, lb1); gb1 += BK;
        async_load16(gb2, lb2); gb2 += BK;
        async_load16(gb3, lb3); gb3 += BK;
        __syncthreads();

#pragma unroll
        for (int h = 0; h < 2; ++h) {
            bf16x8 afr[4], bfr[4];
            const int hc = (h << 2) | qk;
            const int ccA = (hc ^ (fm & 7)) * 8;
            const int ccB = (hc ^ (fn & 7)) * 8;
#pragma unroll
            for (int i = 0; i < 4; ++i)
                afr[i] = *reinterpret_cast<const bf16x8*>(
                    &As[(fm + i * 16) * BK + ccA]);
#pragma unroll
            for (int j = 0; j < 4; ++j)
                bfr[j] = *reinterpret_cast<const bf16x8*>(
                    &Bs[(fn + j * 16) * BK + ccB]);
#pragma unroll
            for (int i = 0; i < 4; ++i)
#pragma unroll
                for (int j = 0; j < 4; ++j)
                    acc[i][j] = __builtin_amdgcn_mfma_f32_16x16x32_bf16(
                        afr[i], bfr[j], acc[i][j], 0, 0, 0);
        }
        __syncthreads();
    }

#pragma unroll
    for (int i = 0; i < 4; ++i)
#pragma unroll
        for (int j = 0; j < 4; ++j)
#pragma unroll
            for (int r = 0; r < 4; ++r) {
                long long row = brow + wm + i * 16 + (lane >> 4) * 4 + r;
                long long col = bcol + wn + j * 16 + (lane & 15);
                C[row * N + col] = acc[i][j][r];
            }
}

// ---------------------------------------------------------------------------
extern "C" void kernel_launch(void* const* d_in, const int* in_sizes, int n_in,
                              void* d_out, int out_size, void* d_ws, size_t ws_size,
                              hipStream_t stream) {
    const float* hs  = (const float*)d_in[0];   // [4,2048,2048] fp32
    const float* gcp = (const float*)d_in[1];
    const float* ucp = (const float*)d_in[2];
    const float* dcp = (const float*)d_in[3];

    const int M = 8192;        // 4*2048 tokens
    const int H = 2048;
    const int I = 8192;
    const int NW = H * I;
    const int n_ctrl_g = in_sizes[1];
    const int n_ctrl_u = in_sizes[2];
    const int n_ctrl_d = in_sizes[3];

    // workspace layout (all bf16): Xb | Wg | Wu | Wd | inter
    bf16* Xb    = (bf16*)d_ws;
    bf16* Wg    = Xb + (size_t)M * H;
    bf16* Wu    = Wg + (size_t)NW;
    bf16* Wd    = Wu + (size_t)NW;
    bf16* inter = Wd + (size_t)NW;

    const int nX8 = (M * H) / 8;
    cvt_f32_bf16_8_kernel<<<(nX8 + 255) / 256, 256, 0, stream>>>(
        (const float4*)hs, Xb, nX8);

    double step_g = (double)(n_ctrl_g - 1) / (double)(NW - 1);
    double step_u = (double)(n_ctrl_u - 1) / (double)(NW - 1);
    double step_d = (double)(n_ctrl_d - 1) / (double)(NW - 1);
    const int n8 = NW / 8;
    spline_recon8_kernel<<<(n8 + 255) / 256, 256, 0, stream>>>(gcp, Wg, n8, n_ctrl_g, step_g);
    spline_recon8_kernel<<<(n8 + 255) / 256, 256, 0, stream>>>(ucp, Wu, n8, n_ctrl_u, step_u);
    spline_recon8_kernel<<<(n8 + 255) / 256, 256, 0, stream>>>(dcp, Wd, n8, n_ctrl_d, step_d);

    // fused gate+up: inter = silu(X.Wg^T) * (X.Wu^T)   [M, I]
    fused_gate_up_kernel<<<dim3(I / 128, M / 128), 512, 0, stream>>>(
        Xb, Wg, Wu, inter, M, I, H);

    // down: out = inter . Wd^T  (fp32)   [M, H]
    gemm_down2_kernel<<<dim3(H / 256, M / 128), 512, 0, stream>>>(
        inter, Wd, (float*)d_out, M, H, I);
}